// Round 1
// baseline (936.352 us; speedup 1.0000x reference)
//
#include <hip/hip_runtime.h>
#include <math.h>

// Problem constants
#define HDIM 128
#define WDIM 256
#define NPIX (HDIM*WDIM)   // 32768
#define LD 64
#define S 16
#define J 25
#define KS 21
#define NH 8
#define HMLP 32
#define FFN_H 256

__device__ __forceinline__ float gelu_exact(float v) {
    return 0.5f * v * (1.0f + erff(v * 0.70710678118654752440f));
}

// ---------------------------------------------------------------------------
// Kernel 1: per-row modulation gamma/beta.  gb[h*32 + j] = m[h][j]
// ---------------------------------------------------------------------------
__global__ __launch_bounds__(128) void k_mod(
    const float* __restrict__ x, const float* __restrict__ lm_w1,
    const float* __restrict__ lm_b1, const float* __restrict__ lm_w2,
    const float* __restrict__ lm_b2, float* __restrict__ gb)
{
    int h = threadIdx.x;              // 0..127
    float s0 = x[h * WDIM * 66 + 64]; // sin_cos at w=0
    float s1 = x[h * WDIM * 66 + 65];
    float t[32];
#pragma unroll
    for (int j = 0; j < 32; ++j)
        t[j] = gelu_exact(s0 * lm_w1[j] + s1 * lm_w1[32 + j] + lm_b1[j]);
#pragma unroll
    for (int j = 0; j < 32; ++j) {
        float m = lm_b2[j];
#pragma unroll
        for (int cc = 0; cc < 32; ++cc) m += t[cc] * lm_w2[cc * 32 + j];
        gb[h * 32 + j] = m;
    }
}

// ---------------------------------------------------------------------------
// Kernel 2: disco conv + gamma/beta + head MLP + residual -> x2[p*64+c]
// 256 threads = 4 waves; each wave handles 8 consecutive pixels (same h-row).
// ---------------------------------------------------------------------------
__global__ __launch_bounds__(256) void k_disco(
    const float* __restrict__ x, const float* __restrict__ psi,
    const float* __restrict__ disco_w, const float* __restrict__ disco_b,
    const float* __restrict__ gb, const float* __restrict__ h_w1,
    const float* __restrict__ h_b1, const float* __restrict__ h_w2,
    const float* __restrict__ h_b2, float* __restrict__ x2out)
{
    __shared__ alignas(16) float psi_s[4][J * 24];   // stride 24 (pad from 21)
    __shared__ alignas(16) float wp_s[4][J * 16];    // [j][o]
    __shared__ alignas(16) float dw_s[16 * 28];      // disco_w padded stride 28
    __shared__ float db_s[16];
    __shared__ alignas(16) float hw1_s[8 * 516 + 16]; // n*516 + s*32 + c2
    __shared__ float hw2_s[8 * 33];
    __shared__ alignas(16) float hb1_s[8 * 36];
    __shared__ float hb2_s[8];

    const int tid = threadIdx.x;
    const int wid = tid >> 6;
    const int lane = tid & 63;

    // stage block-shared weights
    for (int i = tid; i < 16 * KS; i += 256) dw_s[(i / KS) * 28 + (i % KS)] = disco_w[i];
    if (tid < 16) db_s[tid] = disco_b[tid];
    for (int i = tid; i < 8 * 16 * 32; i += 256) { int n = i >> 9; hw1_s[n * 516 + (i & 511)] = h_w1[i]; }
    if (tid < 256) { int i = tid; hw2_s[(i >> 5) * 33 + (i & 31)] = h_w2[i]; }
    if (tid < 256) { int i = tid; hb1_s[(i >> 5) * 36 + (i & 31)] = h_b1[i]; }
    if (tid < 8) hb2_s[tid] = h_b2[tid];
    __syncthreads();

    const int pbase = (blockIdx.x * 4 + wid) * 8;   // 8 pixels per wave, same row
    const int h = pbase >> 8;
    const int wbase = pbase & 255;

    int rowoff[5];
#pragma unroll
    for (int a = 0; a < 5; ++a) {
        int hh = h + a - 2;
        hh = hh < 0 ? 0 : (hh > HDIM - 1 ? HDIM - 1 : hh);
        rowoff[a] = hh << 8;
    }

    const int c = lane;
    const int n = lane >> 3;

    for (int it = 0; it < 8; ++it) {
        const int p = pbase + it;
        const int w = wbase + it;

        // stage psi[p] -> LDS (padded stride 24)
        for (int idx = lane; idx < J * KS; idx += 64)
            psi_s[wid][(idx / KS) * 24 + (idx % KS)] = psi[p * (J * KS) + idx];
        __syncthreads();

        // Wp[j][o] = sum_k psi[p][j][k] * disco_w[o][k]
#pragma unroll
        for (int i = 0; i < 7; ++i) {
            int e = i * 64 + lane;
            if (e < J * 16) {
                int j = e >> 4, o = e & 15;
                const float* pr = &psi_s[wid][j * 24];
                const float* wr = &dw_s[o * 28];
                float acc = pr[20] * wr[20];
#pragma unroll
                for (int t = 0; t < 5; ++t) {
                    float4 a = *(const float4*)(pr + t * 4);
                    float4 b = *(const float4*)(wr + t * 4);
                    acc += a.x * b.x + a.y * b.y + a.z * b.z + a.w * b.w;
                }
                wp_s[wid][e] = acc;
            }
        }
        __syncthreads();

        // gather 5x5 neighborhood for this lane's channel
        float xg[25];
#pragma unroll
        for (int a = 0; a < 5; ++a)
#pragma unroll
            for (int bj = 0; bj < 5; ++bj) {
                int ww = (w + bj - 2) & 255;
                xg[a * 5 + bj] = x[(rowoff[a] + ww) * 66 + c];
            }

        // y[o] = disco_b[o] + sum_j xg[j]*Wp[j][o]
        float y[16];
#pragma unroll
        for (int o = 0; o < 16; ++o) y[o] = db_s[o];
#pragma unroll
        for (int j = 0; j < J; ++j) {
            float xj = xg[j];
            const float4* wp4 = (const float4*)&wp_s[wid][j * 16];
#pragma unroll
            for (int o4 = 0; o4 < 4; ++o4) {
                float4 wv = wp4[o4];
                y[o4 * 4 + 0] += xj * wv.x;
                y[o4 * 4 + 1] += xj * wv.y;
                y[o4 * 4 + 2] += xj * wv.z;
                y[o4 * 4 + 3] += xj * wv.w;
            }
        }
        // gamma/beta (uniform per row)
#pragma unroll
        for (int o = 0; o < 16; ++o)
            y[o] = y[o] * gb[h * 32 + o] + gb[h * 32 + 16 + o];

        // head MLP: c = n*8+d ; 16 -> 32 (gelu) -> 1
        float t32[32];
        {
            const float4* hb = (const float4*)&hb1_s[n * 36];
#pragma unroll
            for (int c4 = 0; c4 < 8; ++c4) {
                float4 bv = hb[c4];
                t32[c4 * 4 + 0] = bv.x; t32[c4 * 4 + 1] = bv.y;
                t32[c4 * 4 + 2] = bv.z; t32[c4 * 4 + 3] = bv.w;
            }
        }
#pragma unroll
        for (int s = 0; s < 16; ++s) {
            float ys = y[s];
            const float* hr = &hw1_s[n * 516 + s * 32];
#pragma unroll
            for (int c4 = 0; c4 < 8; ++c4) {
                float4 hv = *(const float4*)(hr + c4 * 4);
                t32[c4 * 4 + 0] += ys * hv.x;
                t32[c4 * 4 + 1] += ys * hv.y;
                t32[c4 * 4 + 2] += ys * hv.z;
                t32[c4 * 4 + 3] += ys * hv.w;
            }
        }
        float ho = 0.f;
#pragma unroll
        for (int c2 = 0; c2 < 32; ++c2) {
            float tv = gelu_exact(t32[c2]);
            ho += tv * hw2_s[n * 33 + c2];
        }
        float x2v = ho + hb2_s[n] + xg[12];   // + x_learn residual (center tap)
        x2out[p * 64 + c] = x2v;
        __syncthreads();
    }
}

// ---------------------------------------------------------------------------
// Kernel 3a: FFN stage 1.  f1t[q*32768 + p] = gelu(x_full[p] . f_w1[:,q] + b1)
// 64 threads = 1 wave = 64 pixels; blockIdx encodes (pixel tile, q-chunk).
// ---------------------------------------------------------------------------
__global__ __launch_bounds__(64) void k_ffn1(
    const float* __restrict__ x, const float* __restrict__ x2,
    const float* __restrict__ f_w1, const float* __restrict__ f_b1,
    float* __restrict__ f1t)
{
    __shared__ float x2s[64 * 67];   // [pix][k] stride 67 (2-way free)
    const int tid = threadIdx.x;
    const int qc = blockIdx.x & 3;
    const int p0 = (blockIdx.x >> 2) * 64;

    // stage 64 pixel rows (coalesced over c)
    for (int i = 0; i < 64; ++i)
        x2s[i * 67 + tid] = x2[(p0 + i) * 64 + tid];
    // sin/cos rows
    for (int i = tid; i < 128; i += 64) {
        int pix = i >> 1, u = i & 1;
        x2s[pix * 67 + 64 + u] = x[(p0 + pix) * 66 + 64 + u];
    }
    __syncthreads();

    const int p = p0 + tid;
    float acc[64];
#pragma unroll
    for (int cc = 0; cc < 64; ++cc) acc[cc] = f_b1[qc * 64 + cc];

    for (int k = 0; k < 66; ++k) {
        float xv = x2s[tid * 67 + k];
        const float4* wr = (const float4*)(f_w1 + k * FFN_H + qc * 64);
#pragma unroll
        for (int c4 = 0; c4 < 16; ++c4) {
            float4 wv = wr[c4];
            acc[c4 * 4 + 0] += xv * wv.x;
            acc[c4 * 4 + 1] += xv * wv.y;
            acc[c4 * 4 + 2] += xv * wv.z;
            acc[c4 * 4 + 3] += xv * wv.w;
        }
    }
#pragma unroll
    for (int cc = 0; cc < 64; ++cc) {
        float t = gelu_exact(acc[cc]);
        f1t[(qc * 64 + cc) * NPIX + p] = t;
    }
}

// ---------------------------------------------------------------------------
// Kernel 3b: FFN stage 2 + residual + output assembly.
// 64 threads = 64 pixels; blockIdx encodes (pixel tile, c-half).
// ---------------------------------------------------------------------------
__global__ __launch_bounds__(64) void k_ffn2(
    const float* __restrict__ x, const float* __restrict__ x2,
    const float* __restrict__ f1t, const float* __restrict__ f_w2,
    const float* __restrict__ f_b2, float* __restrict__ out)
{
    const int tid = threadIdx.x;
    const int half = blockIdx.x & 1;
    const int p0 = (blockIdx.x >> 1) * 64;
    const int p = p0 + tid;
    const int cbase = half * 32;

    float acc[32];
#pragma unroll
    for (int cc = 0; cc < 32; ++cc) acc[cc] = f_b2[cbase + cc];

    for (int q = 0; q < FFN_H; ++q) {
        float f1v = f1t[q * NPIX + p];
        const float4* wr = (const float4*)(f_w2 + q * 64 + cbase);
#pragma unroll
        for (int c4 = 0; c4 < 8; ++c4) {
            float4 wv = wr[c4];
            acc[c4 * 4 + 0] += f1v * wv.x;
            acc[c4 * 4 + 1] += f1v * wv.y;
            acc[c4 * 4 + 2] += f1v * wv.z;
            acc[c4 * 4 + 3] += f1v * wv.w;
        }
    }

    // residual + store
    const float4* x2p = (const float4*)(x2 + p * 64 + cbase);
#pragma unroll
    for (int c4 = 0; c4 < 8; ++c4) {
        float4 xv = x2p[c4];
        out[p * 66 + cbase + c4 * 4 + 0] = acc[c4 * 4 + 0] + xv.x;
        out[p * 66 + cbase + c4 * 4 + 1] = acc[c4 * 4 + 1] + xv.y;
        out[p * 66 + cbase + c4 * 4 + 2] = acc[c4 * 4 + 2] + xv.z;
        out[p * 66 + cbase + c4 * 4 + 3] = acc[c4 * 4 + 3] + xv.w;
    }
    if (half) {
        out[p * 66 + 64] = x[p * 66 + 64];
        out[p * 66 + 65] = x[p * 66 + 65];
    }
}

// ---------------------------------------------------------------------------
extern "C" void kernel_launch(void* const* d_in, const int* in_sizes, int n_in,
                              void* d_out, int out_size, void* d_ws, size_t ws_size,
                              hipStream_t stream) {
    const float* x       = (const float*)d_in[0];
    // d_in[1] = nbr (recomputed analytically, unused)
    const float* psi     = (const float*)d_in[2];
    const float* disco_w = (const float*)d_in[3];
    const float* disco_b = (const float*)d_in[4];
    const float* lm_w1   = (const float*)d_in[5];
    const float* lm_b1   = (const float*)d_in[6];
    const float* lm_w2   = (const float*)d_in[7];
    const float* lm_b2   = (const float*)d_in[8];
    const float* h_w1    = (const float*)d_in[9];
    const float* h_b1    = (const float*)d_in[10];
    const float* h_w2    = (const float*)d_in[11];
    const float* h_b2    = (const float*)d_in[12];
    const float* f_w1    = (const float*)d_in[13];
    const float* f_b1    = (const float*)d_in[14];
    const float* f_w2    = (const float*)d_in[15];
    const float* f_b2    = (const float*)d_in[16];
    float* out = (float*)d_out;

    float* gb  = (float*)d_ws;              // 4096 floats
    float* x2  = gb + 4096;                 // 32768*64 floats
    float* f1t = x2 + NPIX * 64;            // 256*32768 floats

    k_mod  <<<1,    128, 0, stream>>>(x, lm_w1, lm_b1, lm_w2, lm_b2, gb);
    k_disco<<<1024, 256, 0, stream>>>(x, psi, disco_w, disco_b, gb,
                                      h_w1, h_b1, h_w2, h_b2, x2);
    k_ffn1 <<<2048, 64,  0, stream>>>(x, x2, f_w1, f_b1, f1t);
    k_ffn2 <<<1024, 64,  0, stream>>>(x, x2, f1t, f_w2, f_b2, out);
}